// Round 7
// baseline (1086.443 us; speedup 1.0000x reference)
//
#include <hip/hip_runtime.h>
#include <hip/hip_bf16.h>

#define N_NODES 50000
#define N_EDGES 800000
#define NODE_DIM 256
#define EDGE_DIM 64
#define HIDDEN 512
#define OUT_DIM 256
#define IN_DIM 320   // EDGE_DIM + NODE_DIM

#define SCAT_BLOCKS ((N_EDGES * 16) / 256)             // 50000 (exact)
#define CW_ELEMS (IN_DIM * HIDDEN + HIDDEN * OUT_DIM)  // 294912
#define CW_BLOCKS ((CW_ELEMS + 255) / 256)             // 1152
#define BC_THREADS (N_NODES * 80)                      // 4,000,000 (exact /256)

typedef __bf16 bf16_t;
typedef bf16_t bf16x8 __attribute__((ext_vector_type(8)));
typedef bf16_t bf16x4 __attribute__((ext_vector_type(4)));
typedef float floatx4 __attribute__((ext_vector_type(4)));

__device__ inline bf16_t to_bf16(float f) {
    __hip_bfloat16 h = __float2bfloat16(f);
    bf16_t b;
    __builtin_memcpy(&b, &h, 2);
    return b;
}

// async 16B global -> LDS (wave-uniform LDS base + lane*16 pattern required)
__device__ inline void async16(const void* g, void* l) {
    __builtin_amdgcn_global_load_lds(
        (const __attribute__((address_space(1))) unsigned int*)g,
        (__attribute__((address_space(3))) unsigned int*)l, 16, 0, 0);
}

// ---------------------------------------------------------------------------
// K1: edge-major scatter-add (f32 atomics, coalesced ef reads) + edge counts
//     + weight bf16-transpose on disjoint trailing blocks.
// 16 threads per edge; thread q handles dims [4q, 4q+4).
// ---------------------------------------------------------------------------
__global__ __launch_bounds__(256) void scatter_and_weights(
    const int* __restrict__ eidx, const float* __restrict__ ef,
    float* __restrict__ agg, int* __restrict__ counts,
    const float* __restrict__ W1, const float* __restrict__ W2,
    bf16_t* __restrict__ W1T, bf16_t* __restrict__ W2T) {
    if (blockIdx.x < SCAT_BLOCKS) {
        int gid = blockIdx.x * 256 + threadIdx.x;
        int e = gid >> 4;   // edge id
        int q = gid & 15;   // float4 chunk within the 64-dim row
        if (e < N_EDGES) {
            int t = min(max(eidx[N_EDGES + e], 0), N_NODES - 1);
            floatx4 v = *reinterpret_cast<const floatx4*>(
                &ef[(size_t)e * EDGE_DIM + q * 4]);
            float* dst = &agg[(size_t)t * EDGE_DIM + q * 4];
            atomicAdd(dst + 0, v[0]);
            atomicAdd(dst + 1, v[1]);
            atomicAdd(dst + 2, v[2]);
            atomicAdd(dst + 3, v[3]);
            if (q == 0) atomicAdd(&counts[t], 1);
        }
    } else {
        int idx = (blockIdx.x - SCAT_BLOCKS) * 256 + threadIdx.x;
        if (idx < IN_DIM * HIDDEN) {
            int k = idx / HIDDEN, n = idx - k * HIDDEN;
            W1T[(size_t)n * IN_DIM + k] = to_bf16(W1[idx]);
        } else {
            int j = idx - IN_DIM * HIDDEN;
            if (j < HIDDEN * OUT_DIM) {
                int k = j / OUT_DIM, n = j - k * OUT_DIM;
                W2T[(size_t)n * HIDDEN + k] = to_bf16(W2[j]);
            }
        }
    }
}

// ---------------------------------------------------------------------------
// K2: combined[n, 0:64]  = agg[n]/max(counts[n],1)   (bf16)
//     combined[n,64:320] = node[n]                   (bf16)
// One bf16x4 (8 B) per thread; all loads/stores coalesced.
// ---------------------------------------------------------------------------
__global__ __launch_bounds__(256) void build_combined(
    const float* __restrict__ agg, const int* __restrict__ counts,
    const float* __restrict__ node, bf16_t* __restrict__ combined) {
    int idx = blockIdx.x * 256 + threadIdx.x;
    if (idx >= BC_THREADS) return;
    int n = idx / 80;
    int q = idx - n * 80;  // 0..79: chunk of 4 elems within the 320-dim row
    floatx4 v;
    if (q < 16) {
        v = *reinterpret_cast<const floatx4*>(&agg[(size_t)n * EDGE_DIM + q * 4]);
        float inv = 1.0f / (float)max(counts[n], 1);
        v *= inv;
    } else {
        v = *reinterpret_cast<const floatx4*>(
            &node[(size_t)n * NODE_DIM + (q - 16) * 4]);
    }
    bf16x4 o;
    o[0] = to_bf16(v[0]);
    o[1] = to_bf16(v[1]);
    o[2] = to_bf16(v[2]);
    o[3] = to_bf16(v[3]);
    *reinterpret_cast<bf16x4*>(&combined[(size_t)n * IN_DIM + q * 4]) = o;
}

// ---------------------------------------------------------------------------
// K3/K4: C[M,N] = act(A[M,K] @ BT[N,K]^T + bias) — verified m97 structure:
// unpadded 128x32 LDS tiles staged via global_load_lds width=16.
// 4 waves 2x2, each 4x4 16x16x32 bf16 MFMAs.  (byte-identical to round 4)
// ---------------------------------------------------------------------------
template <bool RELU, bool OUT_BF16>
__global__ __launch_bounds__(256) void gemm_bt(
    const bf16_t* __restrict__ A, const bf16_t* __restrict__ BT,
    const float* __restrict__ bias, void* __restrict__ Cout,
    int M, int N, int K) {
    __shared__ bf16_t As[128][32];  // unpadded: required by global_load_lds
    __shared__ bf16_t Bs[128][32];

    const int tid = threadIdx.x;
    const int lane = tid & 63;
    const int w = tid >> 6;
    const int wm = (w & 1) * 64;
    const int wn = (w >> 1) * 64;
    const int lrow = lane & 15;
    const int quad = lane >> 4;
    const int kq = quad * 8;
    const int m0 = blockIdx.x * 128;
    const int n0 = blockIdx.y * 128;

    floatx4 acc[4][4] = {};

    const int nkt = K / 32;
    for (int kt = 0; kt < nkt; ++kt) {
        const int k0 = kt * 32;
        __syncthreads();
#pragma unroll
        for (int it = 0; it < 2; ++it) {
            int slot = it * 256 + tid;
            int row = slot >> 2;
            int cg = (slot & 3) * 8;
            int gm = min(m0 + row, M - 1);  // clamp; garbage rows masked in epilogue
            async16(&A[(size_t)gm * K + k0 + cg], (bf16_t*)As + slot * 8);
            async16(&BT[(size_t)(n0 + row) * K + k0 + cg], (bf16_t*)Bs + slot * 8);
        }
        __syncthreads();  // drains vmcnt before LDS reads

        bf16x8 af[4], bfr[4];
#pragma unroll
        for (int mi = 0; mi < 4; ++mi)
            af[mi] = *reinterpret_cast<const bf16x8*>(&As[wm + mi * 16 + lrow][kq]);
#pragma unroll
        for (int ni = 0; ni < 4; ++ni)
            bfr[ni] = *reinterpret_cast<const bf16x8*>(&Bs[wn + ni * 16 + lrow][kq]);
#pragma unroll
        for (int mi = 0; mi < 4; ++mi)
#pragma unroll
            for (int ni = 0; ni < 4; ++ni)
                acc[mi][ni] = __builtin_amdgcn_mfma_f32_16x16x32_bf16(
                    af[mi], bfr[ni], acc[mi][ni], 0, 0, 0);
    }

#pragma unroll
    for (int ni = 0; ni < 4; ++ni) {
        int gn = n0 + wn + ni * 16 + lrow;
        float bv = bias[gn];
#pragma unroll
        for (int mi = 0; mi < 4; ++mi) {
            int gmb = m0 + wm + mi * 16 + quad * 4;
#pragma unroll
            for (int r = 0; r < 4; ++r) {
                int gm = gmb + r;
                if (gm < M) {
                    float v = acc[mi][ni][r] + bv;
                    if (RELU) v = fmaxf(v, 0.0f);
                    if (OUT_BF16)
                        ((bf16_t*)Cout)[(size_t)gm * N + gn] = to_bf16(v);
                    else
                        ((float*)Cout)[(size_t)gm * N + gn] = v;
                }
            }
        }
    }
}

// ---------------------------------------------------------------------------
// Workspace layout (peak 83.8 MB, below the proven 87.8 MB footprint):
//   [0,        51200000)  h   (bf16, written by gemm1)
//   [0,        12800000)  agg (f32)  — aliases h; dead before gemm1 runs
//   [12800000, 13000000)  counts (int) — also dead before gemm1
//   [51200000, 83200000)  combined (bf16)
//   [83200000, 83527680)  W1T
//   [83527680, 83789824)  W2T
// ---------------------------------------------------------------------------
extern "C" void kernel_launch(void* const* d_in, const int* in_sizes, int n_in,
                              void* d_out, int out_size, void* d_ws, size_t ws_size,
                              hipStream_t stream) {
    const float* node = (const float*)d_in[0];
    const int* eidx = (const int*)d_in[1];
    const float* ef = (const float*)d_in[2];
    const float* W1 = (const float*)d_in[3];
    const float* b1 = (const float*)d_in[4];
    const float* W2 = (const float*)d_in[5];
    const float* b2 = (const float*)d_in[6];
    float* out = (float*)d_out;

    char* ws = (char*)d_ws;
    float* agg = (float*)ws;
    int* counts = (int*)(ws + 12800000);
    bf16_t* h = (bf16_t*)ws;
    bf16_t* combined = (bf16_t*)(ws + 51200000);
    bf16_t* W1T = (bf16_t*)(ws + 83200000);
    bf16_t* W2T = (bf16_t*)(ws + 83527680);

    // zero agg + counts (13 MB, contiguous)
    hipMemsetAsync(ws, 0, 13000000, stream);

    scatter_and_weights<<<SCAT_BLOCKS + CW_BLOCKS, 256, 0, stream>>>(
        eidx, ef, agg, counts, W1, W2, W1T, W2T);

    build_combined<<<BC_THREADS / 256, 256, 0, stream>>>(
        agg, counts, node, combined);

    // h = relu(combined @ W1 + b1)   [50000,512] bf16
    gemm_bt<true, true><<<dim3((N_NODES + 127) / 128, HIDDEN / 128), 256, 0, stream>>>(
        combined, W1T, b1, (void*)h, N_NODES, HIDDEN, IN_DIM);

    // out = h @ W2 + b2              [50000,256] f32
    gemm_bt<false, false><<<dim3((N_NODES + 127) / 128, OUT_DIM / 128), 256, 0, stream>>>(
        h, W2T, b2, (void*)out, N_NODES, OUT_DIM, HIDDEN);
}

// Round 11
// 706.754 us; speedup vs baseline: 1.5372x; 1.5372x over previous
//
#include <hip/hip_runtime.h>
#include <hip/hip_bf16.h>

#define N_NODES 50000
#define N_EDGES 800000
#define NODE_DIM 256
#define EDGE_DIM 64
#define HIDDEN 512
#define OUT_DIM 256
#define IN_DIM 320   // EDGE_DIM + NODE_DIM

#define FRONT_BLOCKS 512           // 2 blocks/CU, co-residency enforced by launch_bounds(256,2)
#define FT (FRONT_BLOCKS * 256)    // 131072 threads
#define TOTAL_WAVES (FT / 64)      // 2048 waves
#define SCAN_CHUNKS 196            // ceil(50000/256)

typedef __bf16 bf16_t;
typedef bf16_t bf16x8 __attribute__((ext_vector_type(8)));
typedef bf16_t bf16x4 __attribute__((ext_vector_type(4)));
typedef float floatx4 __attribute__((ext_vector_type(4)));

__device__ inline bf16_t to_bf16(float f) {
    __hip_bfloat16 h = __float2bfloat16(f);
    bf16_t b;
    __builtin_memcpy(&b, &h, 2);
    return b;
}

// async 16B global -> LDS (wave-uniform LDS base + lane*16 pattern required)
__device__ inline void async16(const void* g, void* l) {
    __builtin_amdgcn_global_load_lds(
        (const __attribute__((address_space(1))) unsigned int*)g,
        (__attribute__((address_space(3))) unsigned int*)l, 16, 0, 0);
}

// ---------------------------------------------------------------------------
// Software grid barrier (regular launch; all FRONT_BLOCKS co-resident).
// Arrive counter self-resets (last block zeroes it); release flag is
// monotonic across kernel invocations/graph replays. __device__ globals are
// zero-init at load; invariant: count returns to 0 after each use.
// Stream-serialized launches => no cross-invocation overlap on a slot.
// __threadfence() = agent-scope fence (the portable spelling on this ROCm).
// ---------------------------------------------------------------------------
__device__ int g_bar_count[8];
__device__ int g_bar_release[8];

__device__ inline void gbar(int k) {
    __syncthreads();
    if (threadIdx.x == 0) {
        int gen = __hip_atomic_load(&g_bar_release[k], __ATOMIC_RELAXED,
                                    __HIP_MEMORY_SCOPE_AGENT);
        __threadfence();  // release: publish this block's phase writes
        int old = atomicAdd(&g_bar_count[k], 1);
        if (old == FRONT_BLOCKS - 1) {
            atomicExch(&g_bar_count[k], 0);  // reset for next invocation
            __threadfence();
            atomicAdd(&g_bar_release[k], 1);
        } else {
            while (__hip_atomic_load(&g_bar_release[k], __ATOMIC_RELAXED,
                                     __HIP_MEMORY_SCOPE_AGENT) == gen)
                __builtin_amdgcn_s_sleep(2);
        }
        __threadfence();  // acquire: make all blocks' phase writes visible
    }
    __syncthreads();
}

// ---------------------------------------------------------------------------
// Fused front end: zero+weights -> hist -> scan -> scatter -> gather.
// Algorithms byte-equivalent to the verified round-4 kernels; only the phase
// glue (software barriers instead of kernel launches) changed.
// ---------------------------------------------------------------------------
__global__ __launch_bounds__(256, 2) void fused_front(
    const float* __restrict__ node, const int* __restrict__ eidx,
    const float* __restrict__ ef, const float* __restrict__ W1,
    const float* __restrict__ W2, char* __restrict__ ws) {
    __shared__ int s[256];

    int* counts = (int*)ws;                      //   200,000 B
    int* offsets = (int*)(ws + 200000);          //   200,004 B
    int* cursor = (int*)(ws + 400016);           //   200,000 B
    int* sorted = (int*)(ws + 600016);           // 3,200,000 B
    bf16_t* combined = (bf16_t*)(ws + 4001600);  // 32,000,000 B
    bf16_t* W1T = (bf16_t*)(ws + 87201600);      //   327,680 B
    bf16_t* W2T = (bf16_t*)(ws + 87529280);      //   262,144 B

    const int tid = threadIdx.x;
    const int b = blockIdx.x;
    const int gtid = b * 256 + tid;

    // ---- P0: zero counts + convert weights to transposed bf16 ----
    for (int i = gtid; i < N_NODES; i += FT) counts[i] = 0;
    for (int idx = gtid; idx < IN_DIM * HIDDEN; idx += FT) {
        int k = idx / HIDDEN, n = idx - k * HIDDEN;
        W1T[(size_t)n * IN_DIM + k] = to_bf16(W1[idx]);
    }
    for (int idx = gtid; idx < HIDDEN * OUT_DIM; idx += FT) {
        int k = idx / OUT_DIM, n = idx - k * OUT_DIM;
        W2T[(size_t)n * HIDDEN + k] = to_bf16(W2[idx]);
    }
    gbar(0);

    // ---- P1: histogram of target indices ----
    for (int e = gtid; e < N_EDGES; e += FT) {
        int tg = min(max(eidx[N_EDGES + e], 0), N_NODES - 1);
        atomicAdd(&counts[tg], 1);
    }
    gbar(1);

    // ---- P2: exclusive scan -> offsets, cursor.  Block b handles chunk b;
    //      its base = sum of counts[0 .. b*256) (redundant, cheap: <=50K ints).
    //      counts was written by L1-bypassing atomics; read it AGENT-scope so
    //      P0's write-through zeros in our own L1 can't be served stale. ----
    if (b < SCAN_CHUNKS) {
        const int chunk0 = b * 256;
        int part = 0;
        for (int i = tid; i < chunk0; i += 256)
            part += __hip_atomic_load(&counts[i], __ATOMIC_RELAXED,
                                      __HIP_MEMORY_SCOPE_AGENT);
        s[tid] = part;
        __syncthreads();
#pragma unroll
        for (int off = 128; off > 0; off >>= 1) {
            if (tid < off) s[tid] += s[tid + off];
            __syncthreads();
        }
        int base = s[0];
        __syncthreads();

        int idx = chunk0 + tid;
        int v = (idx < N_NODES)
                    ? __hip_atomic_load(&counts[idx], __ATOMIC_RELAXED,
                                        __HIP_MEMORY_SCOPE_AGENT)
                    : 0;
        s[tid] = v;
        __syncthreads();
#pragma unroll
        for (int off = 1; off < 256; off <<= 1) {
            int u = (tid >= off) ? s[tid - off] : 0;
            __syncthreads();
            s[tid] += u;
            __syncthreads();
        }
        if (idx < N_NODES) {
            int o = base + s[tid] - v;  // exclusive
            offsets[idx] = o;
            cursor[idx] = o;
        }
        if (b == 0 && tid == 0) offsets[N_NODES] = N_EDGES;
    }
    gbar(2);

    // ---- P3: counting-sort scatter of edge ids ----
    for (int e = gtid; e < N_EDGES; e += FT) {
        int tg = min(max(eidx[N_EDGES + e], 0), N_NODES - 1);
        int pos = atomicAdd(&cursor[tg], 1);
        sorted[pos] = e;
    }
    gbar(3);

    // ---- P4: gather + mean + concat + bf16 cast (wave-strided) ----
    {
        const int wv0 = gtid >> 6;
        const int lane = tid & 63;
        const int slot = lane >> 4;  // 0..3 : edge slot
        const int g4 = lane & 15;    // float4 chunk within 64-dim row
        for (int n = wv0; n < N_NODES; n += TOTAL_WAVES) {
            int beg = offsets[n], end = offsets[n + 1];
            int deg = end - beg;

            int myidx = (lane < deg) ? sorted[beg + lane] : -1;

            floatx4 acc = {0.f, 0.f, 0.f, 0.f};
            int nfull = min(deg, 64);
            for (int j = 0; j < nfull; j += 4) {
                int eid = __shfl(myidx, j + slot);
                if (j + slot < nfull) {
                    floatx4 v = *reinterpret_cast<const floatx4*>(
                        &ef[(size_t)eid * EDGE_DIM + g4 * 4]);
                    acc += v;
                }
            }
            for (int j = 64; j < deg; j += 4) {  // rare tail: deg > 64
                int js = j + slot;
                if (js < deg) {
                    int eid = sorted[beg + js];
                    floatx4 v = *reinterpret_cast<const floatx4*>(
                        &ef[(size_t)eid * EDGE_DIM + g4 * 4]);
                    acc += v;
                }
            }

#pragma unroll
            for (int m = 16; m <= 32; m <<= 1) {
                acc[0] += __shfl_xor(acc[0], m);
                acc[1] += __shfl_xor(acc[1], m);
                acc[2] += __shfl_xor(acc[2], m);
                acc[3] += __shfl_xor(acc[3], m);
            }

            float inv = 1.0f / (float)max(deg, 1);
            size_t cb = (size_t)n * IN_DIM;
            if (slot == 0) {  // lanes 0..15 write the 64 edge dims
                bf16x4 o;
                o[0] = to_bf16(acc[0] * inv);
                o[1] = to_bf16(acc[1] * inv);
                o[2] = to_bf16(acc[2] * inv);
                o[3] = to_bf16(acc[3] * inv);
                *reinterpret_cast<bf16x4*>(&combined[cb + g4 * 4]) = o;
            }
            floatx4 nv = *reinterpret_cast<const floatx4*>(
                &node[(size_t)n * NODE_DIM + lane * 4]);
            bf16x4 no;
            no[0] = to_bf16(nv[0]);
            no[1] = to_bf16(nv[1]);
            no[2] = to_bf16(nv[2]);
            no[3] = to_bf16(nv[3]);
            *reinterpret_cast<bf16x4*>(&combined[cb + EDGE_DIM + lane * 4]) = no;
        }
    }
}

// ---------------------------------------------------------------------------
// GEMMs: C[M,N] = act(A[M,K] @ BT[N,K]^T + bias) — verified m97 structure
// (byte-identical to round 4).
// ---------------------------------------------------------------------------
template <bool RELU, bool OUT_BF16>
__global__ __launch_bounds__(256) void gemm_bt(
    const bf16_t* __restrict__ A, const bf16_t* __restrict__ BT,
    const float* __restrict__ bias, void* __restrict__ Cout,
    int M, int N, int K) {
    __shared__ bf16_t As[128][32];  // unpadded: required by global_load_lds
    __shared__ bf16_t Bs[128][32];

    const int tid = threadIdx.x;
    const int lane = tid & 63;
    const int w = tid >> 6;
    const int wm = (w & 1) * 64;
    const int wn = (w >> 1) * 64;
    const int lrow = lane & 15;
    const int quad = lane >> 4;
    const int kq = quad * 8;
    const int m0 = blockIdx.x * 128;
    const int n0 = blockIdx.y * 128;

    floatx4 acc[4][4] = {};

    const int nkt = K / 32;
    for (int kt = 0; kt < nkt; ++kt) {
        const int k0 = kt * 32;
        __syncthreads();
#pragma unroll
        for (int it = 0; it < 2; ++it) {
            int slot = it * 256 + tid;
            int row = slot >> 2;
            int cg = (slot & 3) * 8;
            int gm = min(m0 + row, M - 1);  // clamp; garbage rows masked in epilogue
            async16(&A[(size_t)gm * K + k0 + cg], (bf16_t*)As + slot * 8);
            async16(&BT[(size_t)(n0 + row) * K + k0 + cg], (bf16_t*)Bs + slot * 8);
        }
        __syncthreads();  // drains vmcnt before LDS reads

        bf16x8 af[4], bfr[4];
#pragma unroll
        for (int mi = 0; mi < 4; ++mi)
            af[mi] = *reinterpret_cast<const bf16x8*>(&As[wm + mi * 16 + lrow][kq]);
#pragma unroll
        for (int ni = 0; ni < 4; ++ni)
            bfr[ni] = *reinterpret_cast<const bf16x8*>(&Bs[wn + ni * 16 + lrow][kq]);
#pragma unroll
        for (int mi = 0; mi < 4; ++mi)
#pragma unroll
            for (int ni = 0; ni < 4; ++ni)
                acc[mi][ni] = __builtin_amdgcn_mfma_f32_16x16x32_bf16(
                    af[mi], bfr[ni], acc[mi][ni], 0, 0, 0);
    }

#pragma unroll
    for (int ni = 0; ni < 4; ++ni) {
        int gn = n0 + wn + ni * 16 + lrow;
        float bv = bias[gn];
#pragma unroll
        for (int mi = 0; mi < 4; ++mi) {
            int gmb = m0 + wm + mi * 16 + quad * 4;
#pragma unroll
            for (int r = 0; r < 4; ++r) {
                int gm = gmb + r;
                if (gm < M) {
                    float v = acc[mi][ni][r] + bv;
                    if (RELU) v = fmaxf(v, 0.0f);
                    if (OUT_BF16)
                        ((bf16_t*)Cout)[(size_t)gm * N + gn] = to_bf16(v);
                    else
                        ((float*)Cout)[(size_t)gm * N + gn] = v;
                }
            }
        }
    }
}

// ---------------------------------------------------------------------------
// Workspace: same proven 87.8 MB layout as round 4 (scan temporaries gone).
// 3 launches total; no memset (P0 zeroes counts in-kernel).
// ---------------------------------------------------------------------------
extern "C" void kernel_launch(void* const* d_in, const int* in_sizes, int n_in,
                              void* d_out, int out_size, void* d_ws, size_t ws_size,
                              hipStream_t stream) {
    const float* node = (const float*)d_in[0];
    const int* eidx = (const int*)d_in[1];
    const float* ef = (const float*)d_in[2];
    const float* W1 = (const float*)d_in[3];
    const float* b1 = (const float*)d_in[4];
    const float* W2 = (const float*)d_in[5];
    const float* b2 = (const float*)d_in[6];
    float* out = (float*)d_out;

    char* ws = (char*)d_ws;
    bf16_t* combined = (bf16_t*)(ws + 4001600);  // 32,000,000 B
    bf16_t* h = (bf16_t*)(ws + 36001600);        // 51,200,000 B
    bf16_t* W1T = (bf16_t*)(ws + 87201600);      //    327,680 B
    bf16_t* W2T = (bf16_t*)(ws + 87529280);      //    262,144 B

    fused_front<<<FRONT_BLOCKS, 256, 0, stream>>>(node, eidx, ef, W1, W2, ws);

    // h = relu(combined @ W1 + b1)   [50000,512] bf16
    gemm_bt<true, true><<<dim3((N_NODES + 127) / 128, HIDDEN / 128), 256, 0, stream>>>(
        combined, W1T, b1, (void*)h, N_NODES, HIDDEN, IN_DIM);

    // out = h @ W2 + b2              [50000,256] f32
    gemm_bt<false, false><<<dim3((N_NODES + 127) / 128, OUT_DIM / 128), 256, 0, stream>>>(
        h, W2T, b2, (void*)out, N_NODES, OUT_DIM, HIDDEN);
}